// Round 7
// baseline (944.008 us; speedup 1.0000x reference)
//
#include <hip/hip_runtime.h>

// HBMA fused: full-search block matching (16x16 blocks, +/-4 search) + predicted
// frame gather. N=8, C=3, H=W=1024.
//
// R7: 256-thread wg = 4 INDEPENDENT waves (one block each), sharing one
// cooperatively staged LDS image: ref strip 3x24x72 (zero-padded) + target
// tile 3x16x64, both via global_load_lds width-16 (9 iters x 256 chunks).
// Exactly ONE __syncthreads() (after staging); afterwards waves never sync.
// Per wave = R6's structure (absmax 0): lane = col(16) x dx-group(4), groups
// 0..2 own dx triplets {3g..3g+2} (acc[9dy][3dx] = 27 regs, group 3 idle in
// SAD), 16-lane shfl reduce, in-wave 81-way argmin with ascending-index
// tie-break (jax scan strict <), gather from the LDS strip.
// All addressing 32-bit int offsets (frame = 3M floats). OOB ref chunks load
// from a zeroed 16B block (MV region of d_out, zeroed by init_kernel).

namespace {
constexpr int BLKi  = 16;
constexpr int NSDi  = 4;
constexpr int ND    = 9;
constexpr int NDISP = 81;
constexpr int Nn    = 8;
constexpr int Cc    = 3;
constexpr int Hh    = 1024;
constexpr int Ww    = 1024;
constexpr int BHn   = 64;
constexpr int STRIPW = 64;                    // 4 blocks per wg, side by side
constexpr int SW    = 72;                     // strip width  (64 + 8)
constexpr int SH    = 24;                     // strip height (16 + 8)
constexpr int STRIP_FLOATS = Cc * SH * SW;    // 5184
constexpr int STRIP_CHUNKS = STRIP_FLOATS/4;  // 1296 (72/4=18 per row: no straddle)
constexpr int TGT_FLOATS   = Cc * BLKi * STRIPW; // 3072
constexpr int TGT_CHUNKS   = TGT_FLOATS / 4;  // 768
constexpr int TOT_CHUNKS   = STRIP_CHUNKS + TGT_CHUNKS; // 2064
constexpr int ITERS        = 9;               // ceil(2064/256)
constexpr int LDSF         = ITERS * 256 * 4; // 9216 floats (incl. 960 pad)
constexpr int MV_SIZE = Nn * 2 * BHn * BHn;   // 65536
constexpr int NWG     = Nn * BHn * (Ww / STRIPW); // 8192
}

typedef const __attribute__((address_space(1))) void* gas_ptr;
typedef __attribute__((address_space(3))) void*       las_ptr;

__global__ void init_kernel(float* __restrict__ out) {
    int i = blockIdx.x * 256 + threadIdx.x;
    if (i < MV_SIZE) out[i] = 0.0f;   // MV output = zeros; doubles as zero-source
}

__global__ __launch_bounds__(256, 4) void hbma_kernel(
        const float* __restrict__ ref,
        const float* __restrict__ tgt,
        float* __restrict__ pred,
        const float* __restrict__ zsrc) {
    __shared__ float ldsA[LDSF];               // [strip 5184][target 3072][pad 960]
    __shared__ float costL[4][NDISP];

    const int tid  = (int)threadIdx.x;
    const int wid  = tid >> 6;                 // wave = which of 4 blocks
    const int lane = tid & 63;
    const int w    = (int)blockIdx.x;          // 0..8191
    const int n    = w >> 10;                  // 1024 wg per image
    const int rem  = w & 1023;
    const int Y0   = (rem >> 4) * BLKi;        // block row * 16
    const int X0   = (rem & 15) * STRIPW;      // strip origin
    const float* refn  = ref  + (size_t)n * Cc * Hh * Ww;
    const float* tgtn  = tgt  + (size_t)n * Cc * Hh * Ww;
    float*       predn = pred + (size_t)n * Cc * Hh * Ww;

    // ---- cooperative staging: strip (zero-padded) then target, 16B chunks ----
    #pragma unroll
    for (int i = 0; i < ITERS; ++i) {
        const int ck = i * 256 + tid;          // chunk id
        if (ck < TOT_CHUNKS) {
            const float* src;
            if (ck < STRIP_CHUNKS) {
                const int c    = ck / (SH * SW / 4);           // /432
                const int rm   = ck - c * (SH * SW / 4);
                const int r    = rm / (SW / 4);                // /18
                const int colc = (rm - r * (SW / 4)) * 4;
                const int gy   = Y0 - NSDi + r;
                const int gx   = X0 - NSDi + colc;             // mult of 4: no straddle
                const bool ok  = ((unsigned)gy < (unsigned)Hh) &&
                                 ((unsigned)gx < (unsigned)Ww);
                src = ok ? (refn + (c << 20) + (gy << 10) + gx) : zsrc;
            } else {
                const int tk   = ck - STRIP_CHUNKS;
                const int c    = tk >> 8;                      // 256 chunks/channel
                const int rm2  = tk & 255;
                const int y    = rm2 >> 4;
                const int colc = (rm2 & 15) * 4;
                src = tgtn + (c << 20) + ((Y0 + y) << 10) + X0 + colc;
            }
            // LDS dest: wave-uniform base (i*1024 + wid*256 floats); HW adds lane*16B
            __builtin_amdgcn_global_load_lds((gas_ptr)src,
                    (las_ptr)(ldsA + i * 1024 + (tid & 192) * 4), 16, 0, 0);
        }
    }
    __syncthreads();                           // the ONLY barrier

    // ---- SAD: this wave's block, lane = col(16) x dx-group(4) ----
    const int col  = lane & 15;
    const int g    = lane >> 4;
    const int d0   = g * 3;                    // 0,3,6 (9 = idle group, harmless)
    const int colS = (wid << 4) + col;         // column within strip
    const float* __restrict__ ldsT = ldsA + STRIP_FLOATS;

    float acc[ND][3];
    #pragma unroll
    for (int j = 0; j < ND; ++j) {
        acc[j][0] = 0.0f; acc[j][1] = 0.0f; acc[j][2] = 0.0f;
    }

    #pragma unroll 1
    for (int c = 0; c < Cc; ++c) {
        float T[BLKi];
        #pragma unroll
        for (int y = 0; y < BLKi; ++y)
            T[y] = ldsT[(c * BLKi + y) * STRIPW + colS];

        #pragma unroll
        for (int r = 0; r < SH; ++r) {
            const float* rp = ldsA + (c * SH + r) * SW + colS + d0;
            const float rv0 = rp[0], rv1 = rp[1], rv2 = rp[2];
            #pragma unroll
            for (int j = 0; j < ND; ++j) {
                const int y = r - j;           // compile-time after unroll
                if (y >= 0 && y < BLKi) {
                    const float tv = T[y];
                    acc[j][0] += fabsf(rv0 - tv);
                    acc[j][1] += fabsf(rv1 - tv);
                    acc[j][2] += fabsf(rv2 - tv);
                }
            }
        }
    }

    // ---- reduce over the 16 columns (within each dx-group) ----
    #pragma unroll
    for (int m = 1; m <= 8; m <<= 1)
        #pragma unroll
        for (int j = 0; j < ND; ++j) {
            acc[j][0] += __shfl_xor(acc[j][0], m, 64);
            acc[j][1] += __shfl_xor(acc[j][1], m, 64);
            acc[j][2] += __shfl_xor(acc[j][2], m, 64);
        }

    // ---- publish: lane (g<3, col==j) writes cost[j*9 + 3g + dd] ----
    #pragma unroll
    for (int jj = 0; jj < ND; ++jj) {
        if (g < 3 && col == jj) {
            costL[wid][jj * ND + d0 + 0] = acc[jj][0];
            costL[wid][jj * ND + d0 + 1] = acc[jj][1];
            costL[wid][jj * ND + d0 + 2] = acc[jj][2];
        }
    }
    asm volatile("s_waitcnt lgkmcnt(0)" ::: "memory");   // same-wave LDS visibility

    // ---- in-wave argmin over 81, ascending index wins ties (jax strict <) ----
    float bc = costL[wid][lane];
    int   bj = lane;
    if (lane < NDISP - 64) {
        float c2 = costL[wid][lane + 64];
        if (c2 < bc) { bc = c2; bj = lane + 64; }
    }
    #pragma unroll
    for (int m = 1; m <= 32; m <<= 1) {
        float oc = __shfl_xor(bc, m, 64);
        int   oi = __shfl_xor(bj, m, 64);
        if (oc < bc || (oc == bc && oi < bj)) { bc = oc; bj = oi; }
    }
    const int by = bj / ND;                    // dy + 4
    const int bx = bj % ND;                    // dx + 4

    // ---- gather predicted block from LDS strip (already zero-padded) ----
    #pragma unroll 1
    for (int c = 0; c < Cc; ++c) {
        #pragma unroll
        for (int yy = 0; yy < 4; ++yy) {
            const int y = (g << 2) + yy;
            const float v = ldsA[(c * SH + y + by) * SW + colS + bx];
            predn[(c << 20) + ((Y0 + y) << 10) + X0 + colS] = v;
        }
    }
}

extern "C" void kernel_launch(void* const* d_in, const int* in_sizes, int n_in,
                              void* d_out, int out_size, void* d_ws, size_t ws_size,
                              hipStream_t stream) {
    const float* ref = (const float*)d_in[0];
    const float* tgt = (const float*)d_in[1];
    float* out = (float*)d_out;

    init_kernel<<<dim3((MV_SIZE + 255) / 256), dim3(256), 0, stream>>>(out);

    // zsrc = MV region (zeroed by init_kernel on this stream, never written after)
    hbma_kernel<<<dim3(NWG), dim3(256), 0, stream>>>(ref, tgt, out + MV_SIZE, out);
}

// Round 8
// 211.130 us; speedup vs baseline: 4.4712x; 4.4712x over previous
//
#include <hip/hip_runtime.h>

// HBMA fused: full-search block matching (16x16 blocks, +/-4 search) + predicted
// frame gather. N=8, C=3, H=W=1024.
//
// R8 = R7 with the launch-bounds bug fixed: (256,4) forced a 64-VGPR cap ->
// acc/T spilled to scratch (WRITE_SIZE 2.8GB, 965us). Now (256,2): VGPR
// budget 256/wave, ~140 expected, zero spills. Structure unchanged:
// 256-thread wg = 4 INDEPENDENT waves (one block each), sharing one
// cooperatively staged LDS image: ref strip 3x24x72 (zero-padded) + target
// tile 3x16x64, both via global_load_lds width-16. ONE __syncthreads();
// afterwards waves never interact. Per wave: lane = col(16) x dx-group(4),
// groups 0..2 own dx triplets (acc[9][3]=27 regs, group 3 idle in SAD),
// 16-lane shfl reduce, in-wave 81-way argmin (ascending-index tie-break =
// jax scan strict <), gather from LDS strip. 32-bit addressing throughout.
// OOB ref chunks load from a zeroed 16B block (MV region, zeroed each launch).

namespace {
constexpr int BLKi  = 16;
constexpr int NSDi  = 4;
constexpr int ND    = 9;
constexpr int NDISP = 81;
constexpr int Nn    = 8;
constexpr int Cc    = 3;
constexpr int Hh    = 1024;
constexpr int Ww    = 1024;
constexpr int BHn   = 64;
constexpr int STRIPW = 64;                    // 4 blocks per wg, side by side
constexpr int SW    = 72;                     // strip width  (64 + 8)
constexpr int SH    = 24;                     // strip height (16 + 8)
constexpr int STRIP_FLOATS = Cc * SH * SW;    // 5184
constexpr int STRIP_CHUNKS = STRIP_FLOATS/4;  // 1296 (72/4=18 per row: no straddle)
constexpr int TGT_FLOATS   = Cc * BLKi * STRIPW; // 3072
constexpr int TGT_CHUNKS   = TGT_FLOATS / 4;  // 768
constexpr int TOT_CHUNKS   = STRIP_CHUNKS + TGT_CHUNKS; // 2064
constexpr int ITERS        = 9;               // ceil(2064/256)
constexpr int LDSF         = ITERS * 256 * 4; // 9216 floats (incl. 960 pad)
constexpr int MV_SIZE = Nn * 2 * BHn * BHn;   // 65536
constexpr int NWG     = Nn * BHn * (Ww / STRIPW); // 8192
}

typedef const __attribute__((address_space(1))) void* gas_ptr;
typedef __attribute__((address_space(3))) void*       las_ptr;

__global__ void init_kernel(float* __restrict__ out) {
    int i = blockIdx.x * 256 + threadIdx.x;
    if (i < MV_SIZE) out[i] = 0.0f;   // MV output = zeros; doubles as zero-source
}

__global__ __launch_bounds__(256, 2) void hbma_kernel(
        const float* __restrict__ ref,
        const float* __restrict__ tgt,
        float* __restrict__ pred,
        const float* __restrict__ zsrc) {
    __shared__ float ldsA[LDSF];               // [strip 5184][target 3072][pad 960]
    __shared__ float costL[4][NDISP];

    const int tid  = (int)threadIdx.x;
    const int wid  = tid >> 6;                 // wave = which of 4 blocks
    const int lane = tid & 63;
    const int w    = (int)blockIdx.x;          // 0..8191
    const int n    = w >> 10;                  // 1024 wg per image
    const int rem  = w & 1023;
    const int Y0   = (rem >> 4) * BLKi;        // block row * 16
    const int X0   = (rem & 15) * STRIPW;      // strip origin
    const float* refn  = ref  + (size_t)n * Cc * Hh * Ww;
    const float* tgtn  = tgt  + (size_t)n * Cc * Hh * Ww;
    float*       predn = pred + (size_t)n * Cc * Hh * Ww;

    // ---- cooperative staging: strip (zero-padded) then target, 16B chunks ----
    #pragma unroll
    for (int i = 0; i < ITERS; ++i) {
        const int ck = i * 256 + tid;          // chunk id
        if (ck < TOT_CHUNKS) {
            const float* src;
            if (ck < STRIP_CHUNKS) {
                const int c    = ck / (SH * SW / 4);           // /432
                const int rm   = ck - c * (SH * SW / 4);
                const int r    = rm / (SW / 4);                // /18
                const int colc = (rm - r * (SW / 4)) * 4;
                const int gy   = Y0 - NSDi + r;
                const int gx   = X0 - NSDi + colc;             // mult of 4: no straddle
                const bool ok  = ((unsigned)gy < (unsigned)Hh) &&
                                 ((unsigned)gx < (unsigned)Ww);
                src = ok ? (refn + (c << 20) + (gy << 10) + gx) : zsrc;
            } else {
                const int tk   = ck - STRIP_CHUNKS;
                const int c    = tk >> 8;                      // 256 chunks/channel
                const int rm2  = tk & 255;
                const int y    = rm2 >> 4;
                const int colc = (rm2 & 15) * 4;
                src = tgtn + (c << 20) + ((Y0 + y) << 10) + X0 + colc;
            }
            // LDS dest: wave-uniform base (i*1024 + wid*256 floats); HW adds lane*16B
            __builtin_amdgcn_global_load_lds((gas_ptr)src,
                    (las_ptr)(ldsA + i * 1024 + (tid & 192) * 4), 16, 0, 0);
        }
    }
    __syncthreads();                           // the ONLY barrier

    // ---- SAD: this wave's block, lane = col(16) x dx-group(4) ----
    const int col  = lane & 15;
    const int g    = lane >> 4;
    const int d0   = g * 3;                    // 0,3,6 (9 = idle group, harmless)
    const int colS = (wid << 4) + col;         // column within strip
    const float* __restrict__ ldsT = ldsA + STRIP_FLOATS;

    float acc[ND][3];
    #pragma unroll
    for (int j = 0; j < ND; ++j) {
        acc[j][0] = 0.0f; acc[j][1] = 0.0f; acc[j][2] = 0.0f;
    }

    #pragma unroll 1
    for (int c = 0; c < Cc; ++c) {
        float T[BLKi];
        #pragma unroll
        for (int y = 0; y < BLKi; ++y)
            T[y] = ldsT[(c * BLKi + y) * STRIPW + colS];

        #pragma unroll
        for (int r = 0; r < SH; ++r) {
            const float* rp = ldsA + (c * SH + r) * SW + colS + d0;
            const float rv0 = rp[0], rv1 = rp[1], rv2 = rp[2];
            #pragma unroll
            for (int j = 0; j < ND; ++j) {
                const int y = r - j;           // compile-time after unroll
                if (y >= 0 && y < BLKi) {
                    const float tv = T[y];
                    acc[j][0] += fabsf(rv0 - tv);
                    acc[j][1] += fabsf(rv1 - tv);
                    acc[j][2] += fabsf(rv2 - tv);
                }
            }
        }
    }

    // ---- reduce over the 16 columns (within each dx-group) ----
    #pragma unroll
    for (int m = 1; m <= 8; m <<= 1)
        #pragma unroll
        for (int j = 0; j < ND; ++j) {
            acc[j][0] += __shfl_xor(acc[j][0], m, 64);
            acc[j][1] += __shfl_xor(acc[j][1], m, 64);
            acc[j][2] += __shfl_xor(acc[j][2], m, 64);
        }

    // ---- publish: lane (g<3, col==j) writes cost[j*9 + 3g + dd] ----
    #pragma unroll
    for (int jj = 0; jj < ND; ++jj) {
        if (g < 3 && col == jj) {
            costL[wid][jj * ND + d0 + 0] = acc[jj][0];
            costL[wid][jj * ND + d0 + 1] = acc[jj][1];
            costL[wid][jj * ND + d0 + 2] = acc[jj][2];
        }
    }
    asm volatile("s_waitcnt lgkmcnt(0)" ::: "memory");   // same-wave LDS visibility

    // ---- in-wave argmin over 81, ascending index wins ties (jax strict <) ----
    float bc = costL[wid][lane];
    int   bj = lane;
    if (lane < NDISP - 64) {
        float c2 = costL[wid][lane + 64];
        if (c2 < bc) { bc = c2; bj = lane + 64; }
    }
    #pragma unroll
    for (int m = 1; m <= 32; m <<= 1) {
        float oc = __shfl_xor(bc, m, 64);
        int   oi = __shfl_xor(bj, m, 64);
        if (oc < bc || (oc == bc && oi < bj)) { bc = oc; bj = oi; }
    }
    const int by = bj / ND;                    // dy + 4
    const int bx = bj % ND;                    // dx + 4

    // ---- gather predicted block from LDS strip (already zero-padded) ----
    #pragma unroll 1
    for (int c = 0; c < Cc; ++c) {
        #pragma unroll
        for (int yy = 0; yy < 4; ++yy) {
            const int y = (g << 2) + yy;
            const float v = ldsA[(c * SH + y + by) * SW + colS + bx];
            predn[(c << 20) + ((Y0 + y) << 10) + X0 + colS] = v;
        }
    }
}

extern "C" void kernel_launch(void* const* d_in, const int* in_sizes, int n_in,
                              void* d_out, int out_size, void* d_ws, size_t ws_size,
                              hipStream_t stream) {
    const float* ref = (const float*)d_in[0];
    const float* tgt = (const float*)d_in[1];
    float* out = (float*)d_out;

    init_kernel<<<dim3((MV_SIZE + 255) / 256), dim3(256), 0, stream>>>(out);

    // zsrc = MV region (zeroed by init_kernel on this stream, never written after)
    hbma_kernel<<<dim3(NWG), dim3(256), 0, stream>>>(ref, tgt, out + MV_SIZE, out);
}